// Round 7
// baseline (350.977 us; speedup 1.0000x reference)
//
#include <hip/hip_runtime.h>
#include <stdint.h>

#define S_LEN 4096
#define HDIM  2048
#define NHEAD 16
#define HD    128
#define WIN   1024

typedef float  f32x4  __attribute__((ext_vector_type(4)));
typedef float  f32x4v __attribute__((ext_vector_type(4)));
typedef __bf16 bf16x8 __attribute__((ext_vector_type(8)));
typedef short  short8 __attribute__((ext_vector_type(8)));
typedef short  short4v __attribute__((ext_vector_type(4)));

static __device__ __forceinline__ short f2bf(float f) {
  union { float f; uint32_t u; } v; v.f = f;
  uint32_t r = (v.u + 0x7FFFu + ((v.u >> 16) & 1u)) >> 16;
  return (short)(uint16_t)r;
}

static __device__ __forceinline__ void gload_lds16(const void* g, void* l) {
  __builtin_amdgcn_global_load_lds((__attribute__((address_space(1))) void*)g,
                                   (__attribute__((address_space(3))) void*)l,
                                   16, 0, 0);
}

// ---------------- RMSNorm: f32 x (4096x2048) -> bf16 xn ----------------
__global__ __launch_bounds__(256) void rmsnorm_k(const float* __restrict__ x,
                                                 const float* __restrict__ w,
                                                 short* __restrict__ xn) {
  const int row = blockIdx.x;
  const int t = threadIdx.x;
  const float* xr = x + (size_t)row * HDIM;
  f32x4v a = *(const f32x4v*)&xr[t * 8];
  f32x4v b = *(const f32x4v*)&xr[t * 8 + 4];
  float ss = a.x*a.x + a.y*a.y + a.z*a.z + a.w*a.w
           + b.x*b.x + b.y*b.y + b.z*b.z + b.w*b.w;
#pragma unroll
  for (int d = 1; d < 64; d <<= 1) ss += __shfl_xor(ss, d, 64);
  __shared__ float sred[4];
  if ((t & 63) == 0) sred[t >> 6] = ss;
  __syncthreads();
  float tot = sred[0] + sred[1] + sred[2] + sred[3];
  float rs = rsqrtf(tot * (1.0f / HDIM) + 1e-5f);
  float vv[8] = {a.x, a.y, a.z, a.w, b.x, b.y, b.z, b.w};
  const float* wp = w + t * 8;
  short8 o;
#pragma unroll
  for (int j = 0; j < 8; ++j) o[j] = f2bf(vv[j] * rs * wp[j]);
  *(short8*)&xn[(size_t)row * HDIM + t * 8] = o;
}

// ---------------- f32 -> bf16 weight convert ----------------
__global__ __launch_bounds__(256) void cvt_k(const float* __restrict__ in,
                                             short* __restrict__ out, int n4) {
  int i = blockIdx.x * 256 + threadIdx.x;
  if (i >= n4) return;
  f32x4v v = *(const f32x4v*)&in[(size_t)i * 4];
  short4v o = { f2bf(v.x), f2bf(v.y), f2bf(v.z), f2bf(v.w) };
  *(short4v*)&out[(size_t)i * 4] = o;
}

// ---------------- 256x256 bf16 GEMM, faithful m201 8-phase port --------
// 8 waves (2M x 4N), per-wave 128x64, BK=64, 2 dbuf (128 KB LDS).
// Per K-tile (4 phases), each phase:
//   [ds_read subtile][stage <=1 half-tile][bar][lgkm(0)+schedbar]
//   [setprio(1) 16 MFMA setprio(0)][bar][schedbar]
// Staging by consumption proof: P1 -> B-hi(t+1) (other dbuf);
// P3 -> B-lo(t+2) (B(t) consumed at P2 lgkm0+bar);
// P4 -> A-lo,A-hi(t+2) (A(t) consumed at P3); vmcnt(6) at P4 end
// (ledger: retires exactly tile t+1's 8 loads). Swizzle: phys 16B-slot =
// log ^ (row&7) on stage-source and read (R6-verified, 0 conflicts).
template <int EPI>
__global__ __launch_bounds__(512, 2) void gemm_8p(
    const short* __restrict__ A, const short* __restrict__ Bt,
    int M, int N, int K, float* __restrict__ Cf,
    const float* __restrict__ cosb, const float* __restrict__ sinb,
    short* __restrict__ Qo, short* __restrict__ Ko, short* __restrict__ Vt) {
  __shared__ __align__(16) short lds[2][32768];   // [dbuf][A 16384 | B 16384]
  const int t = threadIdx.x;
  const int wid = t >> 6, l = t & 63;
  const int lr = l & 15, lg = l >> 4;
  const int wm = wid >> 2, wn = wid & 3;

  int bid = blockIdx.x;
  const int nwg = gridDim.x;
  bid = (bid & 7) * (nwg >> 3) + (bid >> 3);      // bijective XCD remap (nwg%8==0)
  const int nby = M >> 8;
  const int by = bid % nby, bx = bid / nby;       // by fastest: share B-panels in L2
  const int brow = by * 256, bcol = bx * 256;

  // staging: thread t -> rows (t>>3)+{0,64}(+128 for hi half), linear dest
  // t*16B; source logical 16B-slot = (t&7) ^ (row&7).
  const int ssl = ((t & 7) ^ ((t >> 3) & 7)) * 8;
  const short* Asrc = A  + (size_t)(brow + (t >> 3)) * K + ssl;
  const short* Bsrc = Bt + (size_t)(bcol + (t >> 3)) * K + ssl;

  // half-tile stage: half=0 rows 0-127, half=1 rows 128-255 (2 gloads)
#define ST_A(d, kt, half) do {                                                  \
    gload_lds16(Asrc + (size_t)((half) * 128     ) * K + (kt),                  \
                &lds[d][(half) * 8192 + t * 8]);                                \
    gload_lds16(Asrc + (size_t)((half) * 128 + 64) * K + (kt),                  \
                &lds[d][(half) * 8192 + 4096 + t * 8]);                         \
  } while (0)
#define ST_B(d, kt, half) do {                                                  \
    gload_lds16(Bsrc + (size_t)((half) * 128     ) * K + (kt),                  \
                &lds[d][16384 + (half) * 8192 + t * 8]);                        \
    gload_lds16(Bsrc + (size_t)((half) * 128 + 64) * K + (kt),                  \
                &lds[d][16384 + (half) * 8192 + 4096 + t * 8]);                 \
  } while (0)

#define BAR_SCHED  __builtin_amdgcn_s_barrier(); __builtin_amdgcn_sched_barrier(0)
#define LGKM0      asm volatile("s_waitcnt lgkmcnt(0)" ::: "memory");           \
                   __builtin_amdgcn_sched_barrier(0)

  f32x4 acc[8][4] = {};
  const int nt = K >> 6;

  // read offsets (shorts)
  const int s0 = ((lg     ) ^ (lr & 7)) * 8;
  const int s1 = ((lg + 4) ^ (lr & 7)) * 8;
  const int aB = (wm * 128 + lr) * 64;
  const int bB = 16384 + (wn * 64 + lr) * 64;

  // ---- prologue: K0 complete (8 loads) + K1 {A-lo,A-hi,B-lo} (6) ----
  ST_A(0, 0, 0); ST_A(0, 0, 1); ST_B(0, 0, 0); ST_B(0, 0, 1);
  if (nt > 1) { ST_A(1, 64, 0); ST_A(1, 64, 1); ST_B(1, 64, 0); }
  if (nt > 1) asm volatile("s_waitcnt vmcnt(6)" ::: "memory");
  else        asm volatile("s_waitcnt vmcnt(0)" ::: "memory");
  BAR_SCHED;

  for (int kt = 0; kt < nt; ++kt) {
    const int d = kt & 1;
    const short* P = &lds[d][0];
    bf16x8 a03[4][2], a47[4][2], b01[2][2], b23[2][2];

    // ================= phase 1: q(m0-3, n0-1) =================
#pragma unroll
    for (int m = 0; m < 4; ++m) {
      a03[m][0] = *(const bf16x8*)&P[aB + m * 1024 + s0];
      a03[m][1] = *(const bf16x8*)&P[aB + m * 1024 + s1];
    }
#pragma unroll
    for (int n = 0; n < 2; ++n) {
      b01[n][0] = *(const bf16x8*)&P[bB + n * 1024 + s0];
      b01[n][1] = *(const bf16x8*)&P[bB + n * 1024 + s1];
    }
    if (kt + 1 < nt) ST_B(d ^ 1, (kt + 1) << 6, 1);
    BAR_SCHED;
    LGKM0;
    __builtin_amdgcn_s_setprio(1);
#pragma unroll
    for (int m = 0; m < 4; ++m)
#pragma unroll
      for (int n = 0; n < 2; ++n) {
        acc[m][n] = __builtin_amdgcn_mfma_f32_16x16x32_bf16(a03[m][0], b01[n][0], acc[m][n], 0, 0, 0);
        acc[m][n] = __builtin_amdgcn_mfma_f32_16x16x32_bf16(a03[m][1], b01[n][1], acc[m][n], 0, 0, 0);
      }
    __builtin_amdgcn_s_setprio(0);
    BAR_SCHED;

    // ================= phase 2: q(m0-3, n2-3) =================
#pragma unroll
    for (int n = 0; n < 2; ++n) {
      b23[n][0] = *(const bf16x8*)&P[bB + (n + 2) * 1024 + s0];
      b23[n][1] = *(const bf16x8*)&P[bB + (n + 2) * 1024 + s1];
    }
    BAR_SCHED;
    LGKM0;
    __builtin_amdgcn_s_setprio(1);
#pragma unroll
    for (int m = 0; m < 4; ++m)
#pragma unroll
      for (int n = 0; n < 2; ++n) {
        acc[m][n + 2] = __builtin_amdgcn_mfma_f32_16x16x32_bf16(a03[m][0], b23[n][0], acc[m][n + 2], 0, 0, 0);
        acc[m][n + 2] = __builtin_amdgcn_mfma_f32_16x16x32_bf16(a03[m][1], b23[n][1], acc[m][n + 2], 0, 0, 0);
      }
    __builtin_amdgcn_s_setprio(0);
    BAR_SCHED;

    // ================= phase 3: q(m4-7, n2-3) =================
#pragma unroll
    for (int m = 0; m < 4; ++m) {
      a47[m][0] = *(const bf16x8*)&P[aB + (m + 4) * 1024 + s0];
      a47[m][1] = *(const bf16x8*)&P[aB + (m + 4) * 1024 + s1];
    }
    if (kt + 2 < nt) ST_B(d, (kt + 2) << 6, 0);
    BAR_SCHED;
    LGKM0;
    __builtin_amdgcn_s_setprio(1);
#pragma unroll
    for (int m = 0; m < 4; ++m)
#pragma unroll
      for (int n = 0; n < 2; ++n) {
        acc[m + 4][n + 2] = __builtin_amdgcn_mfma_f32_16x16x32_bf16(a47[m][0], b23[n][0], acc[m + 4][n + 2], 0, 0, 0);
        acc[m + 4][n + 2] = __builtin_amdgcn_mfma_f32_16x16x32_bf16(a47[m][1], b23[n][1], acc[m + 4][n + 2], 0, 0, 0);
      }
    __builtin_amdgcn_s_setprio(0);
    BAR_SCHED;

    // ================= phase 4: q(m4-7, n0-1) =================
    if (kt + 2 < nt) { ST_A(d, (kt + 2) << 6, 0); ST_A(d, (kt + 2) << 6, 1); }
    BAR_SCHED;
    __builtin_amdgcn_s_setprio(1);
#pragma unroll
    for (int m = 0; m < 4; ++m)
#pragma unroll
      for (int n = 0; n < 2; ++n) {
        acc[m + 4][n] = __builtin_amdgcn_mfma_f32_16x16x32_bf16(a47[m][0], b01[n][0], acc[m + 4][n], 0, 0, 0);
        acc[m + 4][n] = __builtin_amdgcn_mfma_f32_16x16x32_bf16(a47[m][1], b01[n][1], acc[m + 4][n], 0, 0, 0);
      }
    __builtin_amdgcn_s_setprio(0);
    if (kt + 2 < nt)      asm volatile("s_waitcnt vmcnt(6)" ::: "memory");
    else if (kt + 1 < nt) asm volatile("s_waitcnt vmcnt(0)" ::: "memory");
    BAR_SCHED;
  }
#undef ST_A
#undef ST_B
#undef BAR_SCHED
#undef LGKM0

  const int row0 = brow + wm * 128, col0 = bcol + wn * 64;
  if (EPI == 0) {
#pragma unroll
    for (int m = 0; m < 8; ++m)
#pragma unroll
      for (int n = 0; n < 4; ++n)
#pragma unroll
        for (int r = 0; r < 4; ++r)
          Cf[(size_t)(row0 + m * 16 + lg * 4 + r) * N + col0 + n * 16 + lr] = acc[m][n][r];
  } else {
    const int sec = col0 >> 11;                 // uniform per wave
    const int headc = (col0 & 2047) >> 7;
    const bool rope = (sec < 2) && ((col0 & 127) == 0);
#pragma unroll
    for (int m = 0; m < 8; ++m) {
#pragma unroll
      for (int r = 0; r < 4; ++r) {
        const int s = row0 + m * 16 + lg * 4 + r;
        float v0 = acc[m][0][r], v1 = acc[m][1][r];
        float v2 = acc[m][2][r], v3 = acc[m][3][r];
        if (rope) {
          const int d0 = lr;
          float c0 = cosb[s * 32 + d0],      sn0 = sinb[s * 32 + d0];
          float c1 = cosb[s * 32 + d0 + 16], sn1 = sinb[s * 32 + d0 + 16];
          float t0 = v0 * c0 - v1 * sn0;
          float t1 = v1 * c1 + v0 * sn1;
          v0 = t0; v1 = t1;
        }
        float vv[4] = {v0, v1, v2, v3};
#pragma unroll
        for (int n = 0; n < 4; ++n) {
          const int col = col0 + n * 16 + lr;
          const int d = col & 127;
          if (sec == 0)
            Qo[((size_t)headc * S_LEN + s) * HD + d] = f2bf(vv[n] * 0.08838834764831845f);
          else if (sec == 1)
            Ko[((size_t)headc * S_LEN + s) * HD + d] = f2bf(vv[n]);
          else
            Vt[((size_t)headc * HD + d) * S_LEN + s] = f2bf(vv[n]);
        }
      }
    }
  }
}

// ---------------- sliding-window flash attention ----------------
__global__ __launch_bounds__(256) void attn_k(const short* __restrict__ Q,
                                              const short* __restrict__ Kk,
                                              const short* __restrict__ Vt,
                                              short* __restrict__ Ao) {
  __shared__ __align__(16) short Kl[64 * HD];
  __shared__ __align__(16) short Vl[HD * 64];
  __shared__ __align__(16) short Pl[4][16 * 72];
  const int head = blockIdx.y;
  int bxx = blockIdx.x;
  bxx = ((bxx & 7) << 3) | (bxx >> 3);
  const int qb = bxx * 64;
  const int w = threadIdx.x >> 6, l = threadIdx.x & 63;
  const int lr = l & 15, lg = l >> 4;
  const int q0w = qb + w * 16;
  const short* Qh = Q  + (size_t)head * S_LEN * HD;
  const short* Kh = Kk + (size_t)head * S_LEN * HD;
  const short* Vh = Vt + (size_t)head * HD * S_LEN;

  bf16x8 qf[4];
#pragma unroll
  for (int kk = 0; kk < 4; ++kk)
    qf[kk] = *(const bf16x8*)&Qh[(size_t)(q0w + lr) * HD + kk * 32 + lg * 8];

  f32x4 oacc[8] = {};
  float mrow[4], lrow[4];
#pragma unroll
  for (int r = 0; r < 4; ++r) { mrow[r] = -1e30f; lrow[r] = 0.0f; }

  const int k_begin = (qb >= WIN) ? (qb - WIN) : 0;
  const int nt = (qb + 64 - k_begin) >> 6;
  const int swz = (lr & 7) << 4;

  for (int tkv = 0; tkv < nt; ++tkv) {
    const int k0 = k_begin + tkv * 64;
#pragma unroll
    for (int i = 0; i < 4; ++i) {
      const int row = i * 16 + w * 4 + (l >> 4);
      gload_lds16(Kh + (size_t)(k0 + row) * HD + (((l & 15) ^ (row & 7)) * 8),
                  &Kl[(i * 16 + w * 4) * HD]);
    }
#pragma unroll
    for (int i = 0; i < 4; ++i) {
      const int row = i * 32 + w * 8 + (l >> 3);
      gload_lds16(Vh + (size_t)row * S_LEN + k0 + (((l & 7) ^ (row & 7)) * 8),
                  &Vl[(i * 32 + w * 8) * 64]);
    }
    __syncthreads();

    f32x4 sacc[4] = {};
#pragma unroll
    for (int nf = 0; nf < 4; ++nf) {
      const char* kb = (const char*)Kl + (nf * 16 + lr) * 256;
      bf16x8 kf[4];
#pragma unroll
      for (int kk = 0; kk < 4; ++kk)
        kf[kk] = *(const bf16x8*)(kb + ((kk * 64 + lg * 16) ^ swz));
#pragma unroll
      for (int kk = 0; kk < 4; ++kk)
        sacc[nf] = __builtin_amdgcn_mfma_f32_16x16x32_bf16(qf[kk], kf[kk], sacc[nf], 0, 0, 0);
    }

    const bool full = (k0 + 63 <= q0w) && (k0 >= q0w + 15 - WIN);
    float scl[4];
#pragma unroll
    for (int r = 0; r < 4; ++r) {
      const int i = q0w + lg * 4 + r;
      float sv[4];
#pragma unroll
      for (int nf = 0; nf < 4; ++nf) sv[nf] = sacc[nf][r];
      if (!full) {
#pragma unroll
        for (int nf = 0; nf < 4; ++nf) {
          const int j = k0 + nf * 16 + lr;
          if (!((j <= i) && (j + WIN >= i))) sv[nf] = -1e30f;
        }
      }
      float mx = fmaxf(fmaxf(sv[0], sv[1]), fmaxf(sv[2], sv[3]));
#pragma unroll
      for (int d = 1; d < 16; d <<= 1) mx = fmaxf(mx, __shfl_xor(mx, d, 64));
      const float mn = fmaxf(mrow[r], mx);
      const float sc = __expf(mrow[r] - mn);
      mrow[r] = mn;
      float p[4], rs = 0.0f;
#pragma unroll
      for (int nf = 0; nf < 4; ++nf) { p[nf] = __expf(sv[nf] - mn); rs += p[nf]; }
#pragma unroll
      for (int d = 1; d < 16; d <<= 1) rs += __shfl_xor(rs, d, 64);
      lrow[r] = lrow[r] * sc + rs;
      scl[r] = sc;
#pragma unroll
      for (int nf = 0; nf < 4; ++nf)
        Pl[w][(lg * 4 + r) * 72 + nf * 16 + lr] = f2bf(p[nf]);
    }
#pragma unroll
    for (int df = 0; df < 8; ++df)
#pragma unroll
      for (int r = 0; r < 4; ++r) oacc[df][r] *= scl[r];

    bf16x8 pa[2];
#pragma unroll
    for (int kk2 = 0; kk2 < 2; ++kk2)
      pa[kk2] = *(const bf16x8*)&Pl[w][lr * 72 + kk2 * 32 + lg * 8];

#pragma unroll
    for (int df = 0; df < 8; ++df) {
      const char* vb = (const char*)Vl + (df * 16 + lr) * 128;
#pragma unroll
      for (int kk2 = 0; kk2 < 2; ++kk2) {
        bf16x8 vfrag = *(const bf16x8*)(vb + ((kk2 * 64 + lg * 16) ^ swz));
        oacc[df] = __builtin_amdgcn_mfma_f32_16x16x32_bf16(pa[kk2], vfrag, oacc[df], 0, 0, 0);
      }
    }
    __syncthreads();
  }

  float inv[4];
#pragma unroll
  for (int r = 0; r < 4; ++r) inv[r] = 1.0f / lrow[r];
#pragma unroll
  for (int df = 0; df < 8; ++df)
#pragma unroll
    for (int r = 0; r < 4; ++r) {
      const int s = q0w + lg * 4 + r;
      Ao[(size_t)s * HDIM + head * HD + df * 16 + lr] = f2bf(oacc[df][r] * inv[r]);
    }
}

extern "C" void kernel_launch(void* const* d_in, const int* in_sizes, int n_in,
                              void* d_out, int out_size, void* d_ws, size_t ws_size,
                              hipStream_t stream) {
  const float* x    = (const float*)d_in[0];
  const float* cosb = (const float*)d_in[1];
  const float* sinb = (const float*)d_in[2];
  const float* nw   = (const float*)d_in[3];
  const float* qkvw = (const float*)d_in[4];
  const float* ow   = (const float*)d_in[5];
  float* out = (float*)d_out;

  short* ws = (short*)d_ws;
  short* xn = ws;
  short* wb = xn + (size_t)S_LEN * HDIM;
  short* Qb = wb + (size_t)3 * HDIM * HDIM;
  short* Kb = Qb + (size_t)NHEAD * S_LEN * HD;
  short* Vb = Kb + (size_t)NHEAD * S_LEN * HD;
  short* Ao = xn;

  rmsnorm_k<<<S_LEN, 256, 0, stream>>>(x, nw, xn);
  cvt_k<<<(3 * HDIM * HDIM / 4 + 255) / 256, 256, 0, stream>>>(qkvw, wb, 3 * HDIM * HDIM / 4);
  gemm_8p<1><<<(S_LEN / 256) * (3 * HDIM / 256), 512, 0, stream>>>(
      xn, wb, S_LEN, 3 * HDIM, HDIM, nullptr, cosb, sinb, Qb, Kb, Vb);
  cvt_k<<<(HDIM * HDIM / 4 + 255) / 256, 256, 0, stream>>>(ow, wb, HDIM * HDIM / 4);
  attn_k<<<dim3(S_LEN / 64, NHEAD), 256, 0, stream>>>(Qb, Kb, Vb, Ao);
  gemm_8p<0><<<(S_LEN / 256) * (HDIM / 256), 512, 0, stream>>>(
      Ao, wb, S_LEN, HDIM, HDIM, out, nullptr, nullptr, nullptr, nullptr, nullptr);
}

// Round 9
// 310.831 us; speedup vs baseline: 1.1292x; 1.1292x over previous
//
#include <hip/hip_runtime.h>
#include <stdint.h>

#define S_LEN 4096
#define HDIM  2048
#define NHEAD 16
#define HD    128
#define WIN   1024

typedef float  f32x4  __attribute__((ext_vector_type(4)));
typedef float  f32x4v __attribute__((ext_vector_type(4)));
typedef __bf16 bf16x8 __attribute__((ext_vector_type(8)));
typedef short  short8 __attribute__((ext_vector_type(8)));
typedef short  short4v __attribute__((ext_vector_type(4)));

static __device__ __forceinline__ short f2bf(float f) {
  union { float f; uint32_t u; } v; v.f = f;
  uint32_t r = (v.u + 0x7FFFu + ((v.u >> 16) & 1u)) >> 16;
  return (short)(uint16_t)r;
}

static __device__ __forceinline__ void gload_lds16(const void* g, void* l) {
  __builtin_amdgcn_global_load_lds((__attribute__((address_space(1))) void*)g,
                                   (__attribute__((address_space(3))) void*)l,
                                   16, 0, 0);
}

// ---------------- RMSNorm: f32 x (4096x2048) -> bf16 xn ----------------
__global__ __launch_bounds__(256) void rmsnorm_k(const float* __restrict__ x,
                                                 const float* __restrict__ w,
                                                 short* __restrict__ xn) {
  const int row = blockIdx.x;
  const int t = threadIdx.x;
  const float* xr = x + (size_t)row * HDIM;
  f32x4v a = *(const f32x4v*)&xr[t * 8];
  f32x4v b = *(const f32x4v*)&xr[t * 8 + 4];
  float ss = a.x*a.x + a.y*a.y + a.z*a.z + a.w*a.w
           + b.x*b.x + b.y*b.y + b.z*b.z + b.w*b.w;
#pragma unroll
  for (int d = 1; d < 64; d <<= 1) ss += __shfl_xor(ss, d, 64);
  __shared__ float sred[4];
  if ((t & 63) == 0) sred[t >> 6] = ss;
  __syncthreads();
  float tot = sred[0] + sred[1] + sred[2] + sred[3];
  float rs = rsqrtf(tot * (1.0f / HDIM) + 1e-5f);
  float vv[8] = {a.x, a.y, a.z, a.w, b.x, b.y, b.z, b.w};
  const float* wp = w + t * 8;
  short8 o;
#pragma unroll
  for (int j = 0; j < 8; ++j) o[j] = f2bf(vv[j] * rs * wp[j]);
  *(short8*)&xn[(size_t)row * HDIM + t * 8] = o;
}

// ---------------- f32 -> bf16 weight convert ----------------
__global__ __launch_bounds__(256) void cvt_k(const float* __restrict__ in,
                                             short* __restrict__ out, int n4) {
  int i = blockIdx.x * 256 + threadIdx.x;
  if (i >= n4) return;
  f32x4v v = *(const f32x4v*)&in[(size_t)i * 4];
  short4v o = { f2bf(v.x), f2bf(v.y), f2bf(v.z), f2bf(v.w) };
  *(short4v*)&out[(size_t)i * 4] = o;
}

// ---------------- pipelined 256x128 bf16 GEMM, B^T input ----------------
// VERBATIM restore of the Round-3 kernel (measured: QKV 152us, 0 conflicts).
// 8 waves (4M x 2N), per-wave 64x64 output, BK=64, 3-slot LDS circular buffer.
// Counted vmcnt(6): while computing tile t, tile t+2 stages into slot (t+2)%3.
// T2 XOR swizzle (col8 ^= row&7) on both stage-source and ds_read.
template <int EPI>
__global__ __launch_bounds__(512) void gemm_p(
    const short* __restrict__ A, const short* __restrict__ Bt,
    int M, int N, int K, float* __restrict__ Cf,
    const float* __restrict__ cosb, const float* __restrict__ sinb,
    short* __restrict__ Qo, short* __restrict__ Ko, short* __restrict__ Vt) {
  // per slot: A 256x64 bf16 (16384 shorts) + B 128x64 bf16 (8192 shorts)
  __shared__ __align__(16) short lds[3][24576];
  const int t = threadIdx.x;
  const int wid = t >> 6, l = t & 63;
  const int lr = l & 15, lg = l >> 4;
  const int wm = wid >> 1, wn = wid & 1;

  int bid = blockIdx.x;
  const int nwg = gridDim.x;
  bid = (bid & 7) * (nwg >> 3) + (bid >> 3);   // bijective XCD remap (nwg%8==0)
  const int nbx = N >> 7;
  const int bx = bid % nbx, by = bid / nbx;
  const int brow = by * 256, bcol = bx * 128;

  const int srow7 = (t >> 3) & 7;              // staging row&7
  const int scol = ((t & 7) ^ srow7) * 8;      // inverse-swizzled source col (shorts)

  f32x4 acc[4][4] = {};

  const int nt = K >> 6;

#define STAGE_A(slot, kt, i)                                                     \
  gload_lds16(A + (size_t)(brow + (i) * 64 + (t >> 3)) * K + (kt) + scol,        \
              &lds[slot][(i) * 4096 + t * 8])
#define STAGE_B(slot, kt, i)                                                     \
  gload_lds16(Bt + (size_t)(bcol + (i) * 64 + (t >> 3)) * K + (kt) + scol,       \
              &lds[slot][16384 + (i) * 4096 + t * 8])

  // ---- prologue: stage tiles 0,1 ----
  STAGE_A(0, 0, 0); STAGE_A(0, 0, 1); STAGE_A(0, 0, 2); STAGE_A(0, 0, 3);
  STAGE_B(0, 0, 0); STAGE_B(0, 0, 1);
  STAGE_A(1, 64, 0); STAGE_A(1, 64, 1); STAGE_A(1, 64, 2); STAGE_A(1, 64, 3);
  STAGE_B(1, 64, 0); STAGE_B(1, 64, 1);
  asm volatile("s_waitcnt vmcnt(6)" ::: "memory");   // tile 0 landed
  __builtin_amdgcn_s_barrier();

  const int xo0 = ((lg ^ (lr & 7)) << 3);            // kk=0 read swizzle (shorts)
  const int xo1 = (((4 + lg) ^ (lr & 7)) << 3);      // kk=1

  int slot = 0;
  for (int tt = 0; tt < nt; ++tt) {
    const int s2 = (slot + 2 >= 3) ? slot - 1 : slot + 2;
    const int kt2 = (tt + 2) << 6;
    const bool st = (tt + 2 < nt);
    bf16x8 af[4], bfr[4];

    // ---- phase kk=0 ----
#pragma unroll
    for (int m = 0; m < 4; ++m)
      af[m] = *(const bf16x8*)&lds[slot][(wm * 64 + m * 16 + lr) * 64 + xo0];
#pragma unroll
    for (int n = 0; n < 4; ++n)
      bfr[n] = *(const bf16x8*)&lds[slot][16384 + (wn * 64 + n * 16 + lr) * 64 + xo0];
    if (st) { STAGE_A(s2, kt2, 0); STAGE_A(s2, kt2, 1); STAGE_B(s2, kt2, 0); }
    __builtin_amdgcn_s_barrier();
    asm volatile("s_waitcnt lgkmcnt(0)" ::: "memory");
    __builtin_amdgcn_sched_barrier(0);
    __builtin_amdgcn_s_setprio(1);
#pragma unroll
    for (int m = 0; m < 4; ++m)
#pragma unroll
      for (int n = 0; n < 4; ++n)
        acc[m][n] = __builtin_amdgcn_mfma_f32_16x16x32_bf16(af[m], bfr[n], acc[m][n], 0, 0, 0);
    __builtin_amdgcn_s_setprio(0);
    __builtin_amdgcn_s_barrier();

    // ---- phase kk=1 ----
#pragma unroll
    for (int m = 0; m < 4; ++m)
      af[m] = *(const bf16x8*)&lds[slot][(wm * 64 + m * 16 + lr) * 64 + xo1];
#pragma unroll
    for (int n = 0; n < 4; ++n)
      bfr[n] = *(const bf16x8*)&lds[slot][16384 + (wn * 64 + n * 16 + lr) * 64 + xo1];
    if (st) { STAGE_A(s2, kt2, 2); STAGE_A(s2, kt2, 3); STAGE_B(s2, kt2, 1); }
    if (tt < nt - 2) asm volatile("s_waitcnt vmcnt(6)" ::: "memory");
    else             asm volatile("s_waitcnt vmcnt(0)" ::: "memory");
    __builtin_amdgcn_s_barrier();
    asm volatile("s_waitcnt lgkmcnt(0)" ::: "memory");
    __builtin_amdgcn_sched_barrier(0);
    __builtin_amdgcn_s_setprio(1);
#pragma unroll
    for (int m = 0; m < 4; ++m)
#pragma unroll
      for (int n = 0; n < 4; ++n)
        acc[m][n] = __builtin_amdgcn_mfma_f32_16x16x32_bf16(af[m], bfr[n], acc[m][n], 0, 0, 0);
    __builtin_amdgcn_s_setprio(0);
    __builtin_amdgcn_s_barrier();

    slot = (slot + 1 >= 3) ? 0 : slot + 1;
  }
#undef STAGE_A
#undef STAGE_B

  const int row0 = brow + wm * 64, col0 = bcol + wn * 64;
  if (EPI == 0) {
#pragma unroll
    for (int m = 0; m < 4; ++m)
#pragma unroll
      for (int n = 0; n < 4; ++n)
#pragma unroll
        for (int r = 0; r < 4; ++r)
          Cf[(size_t)(row0 + m * 16 + lg * 4 + r) * N + col0 + n * 16 + lr] = acc[m][n][r];
  } else {
    const int sec = col0 >> 11;
    const int headc = (col0 & 2047) >> 7;
    const bool rope = (sec < 2) && ((col0 & 127) == 0);
#pragma unroll
    for (int m = 0; m < 4; ++m) {
#pragma unroll
      for (int r = 0; r < 4; ++r) {
        const int s = row0 + m * 16 + lg * 4 + r;
        float v0 = acc[m][0][r], v1 = acc[m][1][r];
        float v2 = acc[m][2][r], v3 = acc[m][3][r];
        if (rope) {
          const int d0 = lr;
          float c0 = cosb[s * 32 + d0],      sn0 = sinb[s * 32 + d0];
          float c1 = cosb[s * 32 + d0 + 16], sn1 = sinb[s * 32 + d0 + 16];
          float t0 = v0 * c0 - v1 * sn0;
          float t1 = v1 * c1 + v0 * sn1;
          v0 = t0; v1 = t1;
        }
        float vv[4] = {v0, v1, v2, v3};
#pragma unroll
        for (int n = 0; n < 4; ++n) {
          const int col = col0 + n * 16 + lr;
          const int d = col & 127;
          if (sec == 0)
            Qo[((size_t)headc * S_LEN + s) * HD + d] = f2bf(vv[n] * 0.08838834764831845f);
          else if (sec == 1)
            Ko[((size_t)headc * S_LEN + s) * HD + d] = f2bf(vv[n]);
          else
            Vt[((size_t)headc * HD + d) * S_LEN + s] = f2bf(vv[n]);
        }
      }
    }
  }
}

// ---------------- sliding-window flash attention v3 (2-deep pipeline) ---
// grid (S/64, NHEAD), 4 waves/block, wave w owns 16 q-rows. K/V tiles
// double-buffered: STAGE(t+1) issued BEFORE computing tile t; single
// vmcnt(0)+barrier per iteration (loads fly during compute). Race-free:
// tile-t ds_reads are consumed by MFMAs before the end barrier, so t+1's
// writes (opposite plane) cannot clobber live reads. 73 KB LDS -> 2
// blocks/CU (cross-block TLP covers the serial softmax phase).
__global__ __launch_bounds__(256) void attn_k(const short* __restrict__ Q,
                                              const short* __restrict__ Kk,
                                              const short* __restrict__ Vt,
                                              short* __restrict__ Ao) {
  __shared__ __align__(16) short Kl[2][64 * HD];
  __shared__ __align__(16) short Vl[2][HD * 64];
  __shared__ __align__(16) short Pl[4][16 * 72];
  const int head = blockIdx.y;
  int bxx = blockIdx.x;
  bxx = ((bxx & 7) << 3) | (bxx >> 3);           // XCD remap (bijective, 64=8x8)
  const int qb = bxx * 64;
  const int w = threadIdx.x >> 6, l = threadIdx.x & 63;
  const int lr = l & 15, lg = l >> 4;
  const int q0w = qb + w * 16;
  const short* Qh = Q  + (size_t)head * S_LEN * HD;
  const short* Kh = Kk + (size_t)head * S_LEN * HD;
  const short* Vh = Vt + (size_t)head * HD * S_LEN;

  bf16x8 qf[4];
#pragma unroll
  for (int kk = 0; kk < 4; ++kk)
    qf[kk] = *(const bf16x8*)&Qh[(size_t)(q0w + lr) * HD + kk * 32 + lg * 8];

  f32x4 oacc[8] = {};
  float mrow[4], lrow[4];
#pragma unroll
  for (int r = 0; r < 4; ++r) { mrow[r] = -1e30f; lrow[r] = 0.0f; }

  const int k_begin = (qb >= WIN) ? (qb - WIN) : 0;
  const int nt = (qb + 64 - k_begin) >> 6;
  const int swz = (lr & 7) << 4;

#define STAGE_KV(p, k0) do {                                                   \
    _Pragma("unroll")                                                          \
    for (int i = 0; i < 4; ++i) {                                              \
      const int row = i * 16 + w * 4 + (l >> 4);                               \
      gload_lds16(Kh + (size_t)((k0) + row) * HD + (((l & 15) ^ (row & 7)) * 8),\
                  &Kl[p][(i * 16 + w * 4) * HD]);                              \
    }                                                                          \
    _Pragma("unroll")                                                          \
    for (int i = 0; i < 4; ++i) {                                              \
      const int row = i * 32 + w * 8 + (l >> 3);                               \
      gload_lds16(Vh + (size_t)row * S_LEN + (k0) + (((l & 7) ^ (row & 7)) * 8),\
                  &Vl[p][(i * 32 + w * 8) * 64]);                              \
    }                                                                          \
  } while (0)

  STAGE_KV(0, k_begin);
  asm volatile("s_waitcnt vmcnt(0)" ::: "memory");
  __syncthreads();

  for (int tkv = 0; tkv < nt; ++tkv) {
    const int k0 = k_begin + tkv * 64;
    const int pl = tkv & 1;
    if (tkv + 1 < nt) STAGE_KV(pl ^ 1, k0 + 64);

    // ---- S = Q K^T (16 q x 64 keys) ----
    f32x4 sacc[4] = {};
#pragma unroll
    for (int nf = 0; nf < 4; ++nf) {
      const char* kb = (const char*)&Kl[pl][0] + (nf * 16 + lr) * 256;
      bf16x8 kf[4];
#pragma unroll
      for (int kk = 0; kk < 4; ++kk)
        kf[kk] = *(const bf16x8*)(kb + ((kk * 64 + lg * 16) ^ swz));
#pragma unroll
      for (int kk = 0; kk < 4; ++kk)
        sacc[nf] = __builtin_amdgcn_mfma_f32_16x16x32_bf16(qf[kk], kf[kk], sacc[nf], 0, 0, 0);
    }

    const bool full = (k0 + 63 <= q0w) && (k0 >= q0w + 15 - WIN);
    float scl[4];
#pragma unroll
    for (int r = 0; r < 4; ++r) {
      const int i = q0w + lg * 4 + r;
      float sv[4];
#pragma unroll
      for (int nf = 0; nf < 4; ++nf) sv[nf] = sacc[nf][r];
      if (!full) {
#pragma unroll
        for (int nf = 0; nf < 4; ++nf) {
          const int j = k0 + nf * 16 + lr;
          if (!((j <= i) && (j + WIN >= i))) sv[nf] = -1e30f;
        }
      }
      float mx = fmaxf(fmaxf(sv[0], sv[1]), fmaxf(sv[2], sv[3]));
#pragma unroll
      for (int d = 1; d < 16; d <<= 1) mx = fmaxf(mx, __shfl_xor(mx, d, 64));
      const float mn = fmaxf(mrow[r], mx);
      const float sc = __expf(mrow[r] - mn);
      mrow[r] = mn;
      float p[4], rs = 0.0f;
#pragma unroll
      for (int nf = 0; nf < 4; ++nf) { p[nf] = __expf(sv[nf] - mn); rs += p[nf]; }
#pragma unroll
      for (int d = 1; d < 16; d <<= 1) rs += __shfl_xor(rs, d, 64);
      lrow[r] = lrow[r] * sc + rs;
      scl[r] = sc;
#pragma unroll
      for (int nf = 0; nf < 4; ++nf)
        Pl[w][(lg * 4 + r) * 72 + nf * 16 + lr] = f2bf(p[nf]);
    }
#pragma unroll
    for (int df = 0; df < 8; ++df)
#pragma unroll
      for (int r = 0; r < 4; ++r) oacc[df][r] *= scl[r];

    bf16x8 pa[2];
#pragma unroll
    for (int kk2 = 0; kk2 < 2; ++kk2)
      pa[kk2] = *(const bf16x8*)&Pl[w][lr * 72 + kk2 * 32 + lg * 8];

    // ---- O += P V ----
#pragma unroll
    for (int df = 0; df < 8; ++df) {
      const char* vb = (const char*)&Vl[pl][0] + (df * 16 + lr) * 128;
#pragma unroll
      for (int kk2 = 0; kk2 < 2; ++kk2) {
        bf16x8 vfrag = *(const bf16x8*)(vb + ((kk2 * 64 + lg * 16) ^ swz));
        oacc[df] = __builtin_amdgcn_mfma_f32_16x16x32_bf16(pa[kk2], vfrag, oacc[df], 0, 0, 0);
      }
    }

    if (tkv + 1 < nt) asm volatile("s_waitcnt vmcnt(0)" ::: "memory");
    __syncthreads();
  }
#undef STAGE_KV

  float inv[4];
#pragma unroll
  for (int r = 0; r < 4; ++r) inv[r] = 1.0f / lrow[r];
#pragma unroll
  for (int df = 0; df < 8; ++df)
#pragma unroll
    for (int r = 0; r < 4; ++r) {
      const int s = q0w + lg * 4 + r;
      Ao[(size_t)s * HDIM + head * HD + df * 16 + lr] = f2bf(oacc[df][r] * inv[r]);
    }
}

extern "C" void kernel_launch(void* const* d_in, const int* in_sizes, int n_in,
                              void* d_out, int out_size, void* d_ws, size_t ws_size,
                              hipStream_t stream) {
  const float* x    = (const float*)d_in[0];
  const float* cosb = (const float*)d_in[1];
  const float* sinb = (const float*)d_in[2];
  const float* nw   = (const float*)d_in[3];
  const float* qkvw = (const float*)d_in[4];
  const float* ow   = (const float*)d_in[5];
  float* out = (float*)d_out;

  short* ws = (short*)d_ws;
  short* xn = ws;
  short* wb = xn + (size_t)S_LEN * HDIM;
  short* Qb = wb + (size_t)3 * HDIM * HDIM;
  short* Kb = Qb + (size_t)NHEAD * S_LEN * HD;
  short* Vb = Kb + (size_t)NHEAD * S_LEN * HD;
  short* Ao = xn;

  rmsnorm_k<<<S_LEN, 256, 0, stream>>>(x, nw, xn);
  cvt_k<<<(3 * HDIM * HDIM / 4 + 255) / 256, 256, 0, stream>>>(qkvw, wb, 3 * HDIM * HDIM / 4);
  gemm_p<1><<<(3 * HDIM / 128) * (S_LEN / 256), 512, 0, stream>>>(
      xn, wb, S_LEN, 3 * HDIM, HDIM, nullptr, cosb, sinb, Qb, Kb, Vb);
  cvt_k<<<(HDIM * HDIM / 4 + 255) / 256, 256, 0, stream>>>(ow, wb, HDIM * HDIM / 4);
  attn_k<<<dim3(S_LEN / 64, NHEAD), 256, 0, stream>>>(Qb, Kb, Vb, Ao);
  gemm_p<0><<<(HDIM / 128) * (S_LEN / 256), 512, 0, stream>>>(
      Ao, wb, S_LEN, HDIM, HDIM, out, nullptr, nullptr, nullptr, nullptr, nullptr);
}